// Round 6
// baseline (8214.436 us; speedup 1.0000x reference)
//
#include <hip/hip_runtime.h>

// Problem constants (fixed by the reference)
constexpr int Bc = 64;      // batch
constexpr int Tc = 2048;    // time steps
constexpr int Ic = 3;       // input dim
constexpr int Hc = 512;     // hidden
constexpr float AL = 0.2f;  // ALPHA
constexpr float NS = 0.05f; // NOISE_STD

// New decomposition: 8 h-slices x 32 batch-pair groups = 256 blocks (1/CU).
// Block (s, gb): owns h in [64s, 64s+64) for batches {2gb, 2gb+1}.
// W slice 64x512 fp32 = 128 KB lives in dynamic LDS (cannot be spilled).
constexpr int LDS_W   = 131072;            // 64 rows x 2048 B, XOR-swizzled
constexpr int LDS_RP  = 8192;              // r: [2 parity][2 b][512] swizzled
constexpr int LDS_RED = 64;                // 16-float output reduce scratch
constexpr int LDSB    = LDS_W + LDS_RP + LDS_RED;

// d_ws layout (main path):
//   [0, 1MB)          WH fp32 [512 h][512 k]   (w_rec[h][k], h-major)
//   [1MB, 1MB+512KB)  rbuf u64 [32 gb][2 parity][2 b][512 h] = {tag<<32|f32}
// Fallback path reuses [0,1MB) for WT [k][h].
// ---------------------------------------------------------------------------
__global__ void prep_wh(const float* __restrict__ m, const float* __restrict__ n,
                        const float* __restrict__ rn, float* __restrict__ WH, int R) {
    int id = blockIdx.x * 256 + threadIdx.x;
    if (id >= Hc * Hc) return;
    int h = id >> 9;
    int k = id & (Hc - 1);
    float acc = rn[h * Hc + k];                 // coalesced over k
    for (int r = 0; r < R; ++r)
        acc = fmaf(m[h * R + r], n[k * R + r] * (1.0f / Hc), acc);
    WH[id] = acc;                               // WH[h][k]
}

__global__ void prep_wt(const float* __restrict__ m, const float* __restrict__ n,
                        const float* __restrict__ rn, float* __restrict__ WT, int R) {
    int id = blockIdx.x * 256 + threadIdx.x;
    if (id >= Hc * Hc) return;
    int k = id >> 9;
    int h = id & (Hc - 1);
    float acc = rn[h * Hc + k];
    for (int r = 0; r < R; ++r)
        acc = fmaf(m[h * R + r], n[k * R + r] * (1.0f / Hc), acc);
    WT[id] = acc;                               // WT[k][h]
}

// L2-coherent poll load: bypass L1 (sc0), hit the XCD-shared L2.
__device__ __forceinline__ unsigned long long ld_sc0(const unsigned long long* p) {
    unsigned long long v;
    asm volatile("global_load_dwordx2 %0, %1, off sc0\n\t"
                 "s_waitcnt vmcnt(0)"
                 : "=v"(v) : "v"(p) : "memory");
    return v;
}

// 16B-unit self-swizzle: unit u (4 floats) stored at u ^ ((u>>3)&7).
// Spreads the 16 k-chunks of a wave across all 8 LDS bank-quads.
__device__ __forceinline__ int swz16(int u) { return u ^ ((u >> 3) & 7); }

// ---------------------------------------------------------------------------
// Main kernel: 256 blocks x 1024 threads. bid = s*32 + gb.
// Thread: hl = tid>>4 (0..63, local h), kc = tid&15 (32-k chunk).
// Per step: 8 paired W/r float4 slots -> 64 FMA (both batches share W read),
// 4-step shfl tree over kc, owners (kc<2 -> batch kc) update/publish,
// 896 pollers fetch foreign r words, ONE barrier per step.
// ---------------------------------------------------------------------------
__global__ __launch_bounds__(1024)
void rnn8L(const float* __restrict__ input, const float* __restrict__ noise,
           const float* __restrict__ w_i, const float* __restrict__ s_i,
           const float* __restrict__ WH, const float* __restrict__ w_o,
           const float* __restrict__ s_o, const float* __restrict__ h0,
           float* __restrict__ out, unsigned long long* __restrict__ rbuf) {
    extern __shared__ char smem[];
    float* Wl  = (float*)smem;                    // [64][512] swizzled fp32
    float* rp  = (float*)(smem + LDS_W);          // [2 par][2 b][512] swizzled
    float* red = (float*)(smem + LDS_W + LDS_RP); // [16]

    const int tid   = threadIdx.x;
    const int s     = blockIdx.x >> 5;    // h-slice 0..7
    const int gb    = blockIdx.x & 31;    // batch-pair group
    const int hl    = tid >> 4;           // local h 0..63
    const int kc    = tid & 15;           // k-chunk (k in [32kc, 32kc+32))
    const int kcm   = kc & 7;
    const int hbase = s * 64;
    const int hmy   = hbase + hl;
    const int b0    = gb * 2;

    // --- stage W slice into LDS (one-time): logical [h][unit u] -> swz16(u) ---
    for (int e = tid; e < 64 * 128; e += 1024) {
        const int h = e >> 7, u = e & 127;
        const float4 v = *(const float4*)(WH + (size_t)(hbase + h) * Hc + u * 4);
        ((float4*)Wl)[h * 128 + swz16(u)] = v;
    }
    // --- r_0 (locally computable for all batches) ---
    {
        const int b = tid >> 9, h = tid & 511, u = h >> 2;
        rp[b * 512 + swz16(u) * 4 + (h & 3)] = tanhf(h0[h]);   // parity 0
    }
    const float wo_t = w_o[tid & 511] * s_o[0] * (1.0f / Hc);

    // --- owner state: threads with kc<2 own (batch=kc, h=hmy) ---
    const bool own = (kc < 2);
    const int  ob  = kc;
    float hstate = 0.f, wi0 = 0.f, wi1 = 0.f, wi2 = 0.f;
    const float* noise_b = nullptr;
    const float* inp_b   = nullptr;
    float nz = 0.f, i0 = 0.f, i1 = 0.f, i2 = 0.f;
    if (own) {
        hstate = h0[hmy];
        wi0 = w_i[0 * Hc + hmy] * s_i[0];
        wi1 = w_i[1 * Hc + hmy] * s_i[1];
        wi2 = w_i[2 * Hc + hmy] * s_i[2];
        noise_b = noise + (size_t)(b0 + ob) * Tc * Hc;
        inp_b   = input + (size_t)(b0 + ob) * Tc * Ic;
        nz = noise_b[hmy];
        i0 = inp_b[0]; i1 = inp_b[1]; i2 = inp_b[2];
    }
    unsigned long long* rb_g = rbuf + (size_t)gb * 2048;  // [2 par][2 b][512]

    // --- poller mapping: threads 0..895 <-> 896 foreign (b,h) words ---
    const bool pollv = (tid < 896);
    const int  pb    = (tid >= 448) ? 1 : 0;
    const int  prem  = tid - pb * 448;
    const int  ph    = prem + ((prem >= hbase) ? 64 : 0);

    __syncthreads();

    for (int t = 0; t < Tc; ++t) {
        const int par = t & 1;
        // prefetch next step's drive (owners only)
        const int tn = (t + 1 < Tc) ? t + 1 : t;
        float nz_n = 0.f, i0n = 0.f, i1n = 0.f, i2n = 0.f;
        if (own) {
            nz_n = noise_b[(size_t)tn * Hc + hmy];
            i0n = inp_b[tn * Ic + 0];
            i1n = inp_b[tn * Ic + 1];
            i2n = inp_b[tn * Ic + 2];
        }

        // --- matvec: 8 paired slots; W read shared by both batches ---
        const float4* Wb = (const float4*)(Wl + hl * 512 + kc * 32);
        const float4* r0 = (const float4*)(rp + par * 1024 + 0   + kc * 32);
        const float4* r1 = (const float4*)(rp + par * 1024 + 512 + kc * 32);
        float a0 = 0.f, a1 = 0.f;
        #pragma unroll
        for (int j = 0; j < 8; ++j) {
            const int jj = j ^ kcm;                 // bank-spread slot order
            const float4 wv = Wb[jj];               // logical k = 32kc+4j..+4
            const float4 v0 = r0[jj];               // same logical k (paired)
            const float4 v1 = r1[jj];
            a0 = fmaf(wv.x, v0.x, a0); a0 = fmaf(wv.y, v0.y, a0);
            a0 = fmaf(wv.z, v0.z, a0); a0 = fmaf(wv.w, v0.w, a0);
            a1 = fmaf(wv.x, v1.x, a1); a1 = fmaf(wv.y, v1.y, a1);
            a1 = fmaf(wv.z, v1.z, a1); a1 = fmaf(wv.w, v1.w, a1);
        }
        // --- reduce over the 16 kc lanes (lane bits 0..3 = kc) ---
        #pragma unroll
        for (int m = 1; m <= 8; m <<= 1) {
            a0 += __shfl_xor(a0, m, 64);
            a1 += __shfl_xor(a1, m, 64);
        }

        const unsigned want = (unsigned)(t + 1);
        unsigned long long* slot = rb_g + (size_t)((t + 1) & 1) * 1024;
        float* wp_ = rp + ((t + 1) & 1) * 1024;

        if (own) {
            const float y  = (ob == 0) ? a0 : a1;
            const float di = i0 * wi0 + i1 * wi1 + i2 * wi2;
            hstate = hstate + (NS * nz + AL * di) + AL * (y - hstate);
            const float rv = tanhf(hstate);
            __hip_atomic_store(&slot[ob * 512 + hmy],
                               ((unsigned long long)want << 32) |
                               (unsigned long long)__float_as_uint(rv),
                               __ATOMIC_RELAXED, __HIP_MEMORY_SCOPE_AGENT);
            const int u = hmy >> 2;
            wp_[ob * 512 + swz16(u) * 4 + (hmy & 3)] = rv;
        }

        // --- poll foreign words: 3x sc0 (L2) : 1x agent (MALL) ---
        if (pollv) {
            const unsigned long long* p = &slot[pb * 512 + ph];
            unsigned long long v;
            int it = 0;
            for (;;) {
                if ((it & 3) != 3)
                    v = ld_sc0(p);
                else
                    v = __hip_atomic_load(p, __ATOMIC_RELAXED, __HIP_MEMORY_SCOPE_AGENT);
                if ((unsigned)(v >> 32) == want) break;
                ++it;
            }
            const int u = ph >> 2;
            wp_[pb * 512 + swz16(u) * 4 + (ph & 3)] = __uint_as_float((unsigned)v);
        }
        __syncthreads();   // r_{t+1} complete in parity (t+1)&1

        // --- output for step t (r_seq[t] = tanh(h_{t+1})), rotated over slices ---
        if (((t ^ s) & 7) == 0) {
            const int b = tid >> 9, h = tid & 511, u = h >> 2;
            float p2 = wp_[b * 512 + swz16(u) * 4 + (h & 3)] * wo_t;
            #pragma unroll
            for (int off = 32; off; off >>= 1) p2 += __shfl_xor(p2, off, 64);
            if ((tid & 63) == 0) red[tid >> 6] = p2;
            __syncthreads();
            if (tid == 0) {
                float sum = 0.f;
                #pragma unroll
                for (int q = 0; q < 8; ++q) sum += red[q];
                out[(size_t)b0 * Tc + t] = sum;
            } else if (tid == 512) {
                float sum = 0.f;
                #pragma unroll
                for (int q = 8; q < 16; ++q) sum += red[q];
                out[(size_t)(b0 + 1) * Tc + t] = sum;
            }
        }

        nz = nz_n; i0 = i0n; i1 = i1n; i2 = i2n;
    }
}

// ---------------------------------------------------------------------------
// Fallback (round-1 kernel) — used if ws/dynamic-LDS opt-in unavailable.
// ---------------------------------------------------------------------------
__launch_bounds__(512)
__global__ void rnn_scan_fb(const float* __restrict__ input, const float* __restrict__ noise,
                            const float* __restrict__ w_i, const float* __restrict__ s_i,
                            const float* __restrict__ WT, const float* __restrict__ w_o,
                            const float* __restrict__ s_o, const float* __restrict__ h0,
                            float* __restrict__ out) {
    __shared__ float r_lds[Hc];
    __shared__ float pl[4][Hc];
    __shared__ float wi_lds[Ic][Hc];
    __shared__ float red[8];

    const int tid = threadIdx.x;
    const int b   = blockIdx.x;
    const int g   = tid >> 7;
    const int j   = tid & 127;

    for (int i = 0; i < Ic; ++i) wi_lds[i][tid] = w_i[i * Hc + tid] * s_i[i];

    float h = h0[tid];
    float r_cur = tanhf(h);
    const float wo_h = w_o[tid] * s_o[0] * (1.0f / Hc);
    const float* noise_b = noise + (size_t)b * Tc * Hc;
    const float* inp_b   = input + (size_t)b * Tc * Ic;
    float nz = noise_b[tid];
    float i0 = inp_b[0], i1 = inp_b[1], i2 = inp_b[2];
    const float* Wg = WT + (g * 128) * Hc + 4 * j;
    const float* rg = r_lds + g * 128;
    __syncthreads();

    for (int t = 0; t < Tc; ++t) {
        const int tn = (t + 1 < Tc) ? t + 1 : t;
        const float nz_n = noise_b[(size_t)tn * Hc + tid];
        const float i0n = inp_b[tn * Ic + 0];
        const float i1n = inp_b[tn * Ic + 1];
        const float i2n = inp_b[tn * Ic + 2];

        r_lds[tid] = r_cur;
        __syncthreads();
        float a0 = 0.f, a1 = 0.f, a2 = 0.f, a3 = 0.f;
        #pragma unroll 4
        for (int kk = 0; kk < 128; kk += 4) {
            const float4 rv = *(const float4*)(rg + kk);
            const float4 w0 = *(const float4*)(Wg + (kk + 0) * Hc);
            const float4 w1 = *(const float4*)(Wg + (kk + 1) * Hc);
            const float4 w2 = *(const float4*)(Wg + (kk + 2) * Hc);
            const float4 w3 = *(const float4*)(Wg + (kk + 3) * Hc);
            a0 = fmaf(rv.x, w0.x, a0); a0 = fmaf(rv.y, w1.x, a0);
            a0 = fmaf(rv.z, w2.x, a0); a0 = fmaf(rv.w, w3.x, a0);
            a1 = fmaf(rv.x, w0.y, a1); a1 = fmaf(rv.y, w1.y, a1);
            a1 = fmaf(rv.z, w2.y, a1); a1 = fmaf(rv.w, w3.y, a1);
            a2 = fmaf(rv.x, w0.z, a2); a2 = fmaf(rv.y, w1.z, a2);
            a2 = fmaf(rv.z, w2.z, a2); a2 = fmaf(rv.w, w3.z, a2);
            a3 = fmaf(rv.x, w0.w, a3); a3 = fmaf(rv.y, w1.w, a3);
            a3 = fmaf(rv.z, w2.w, a3); a3 = fmaf(rv.w, w3.w, a3);
        }
        *(float4*)&pl[g][4 * j] = make_float4(a0, a1, a2, a3);
        __syncthreads();

        const float y  = pl[0][tid] + pl[1][tid] + pl[2][tid] + pl[3][tid];
        const float di = i0 * wi_lds[0][tid] + i1 * wi_lds[1][tid] + i2 * wi_lds[2][tid];
        h = h + (NS * nz + AL * di) + AL * (y - h);
        r_cur = tanhf(h);

        float p = r_cur * wo_h;
        #pragma unroll
        for (int off = 32; off; off >>= 1) p += __shfl_xor(p, off, 64);
        if ((tid & 63) == 0) red[tid >> 6] = p;
        __syncthreads();
        if (tid == 0)
            out[(size_t)b * Tc + t] = red[0] + red[1] + red[2] + red[3] +
                                      red[4] + red[5] + red[6] + red[7];
        nz = nz_n; i0 = i0n; i1 = i1n; i2 = i2n;
    }
}

extern "C" void kernel_launch(void* const* d_in, const int* in_sizes, int n_in,
                              void* d_out, int out_size, void* d_ws, size_t ws_size,
                              hipStream_t stream) {
    (void)n_in; (void)out_size;
    const float* input     = (const float*)d_in[0];
    const float* noise     = (const float*)d_in[1];
    const float* w_i       = (const float*)d_in[2];
    const float* s_i       = (const float*)d_in[3];
    const float* m_rec     = (const float*)d_in[4];
    const float* n_rec     = (const float*)d_in[5];
    const float* rec_noise = (const float*)d_in[6];
    const float* w_o       = (const float*)d_in[7];
    const float* s_o       = (const float*)d_in[8];
    const float* h0        = (const float*)d_in[9];
    float* out = (float*)d_out;

    const int R = in_sizes[4] / Hc;

    float* W0 = (float*)d_ws;   // WH (main) or WT (fallback)
    const size_t w_bytes  = (size_t)Hc * Hc * sizeof(float);
    const size_t rb_bytes = (size_t)32 * 2 * 2 * Hc * sizeof(unsigned long long);

    // opt into >64KB dynamic LDS for the main kernel (host-side, capture-safe)
    static hipError_t attr_rc = hipFuncSetAttribute(
        (const void*)rnn8L, hipFuncAttributeMaxDynamicSharedMemorySize, LDSB);

    if (ws_size >= w_bytes + rb_bytes && attr_rc == hipSuccess) {
        unsigned long long* rbuf = (unsigned long long*)((char*)d_ws + w_bytes);
        hipMemsetAsync(rbuf, 0, rb_bytes, stream);  // reset tags (replay-safe)
        prep_wh<<<(Hc * Hc + 255) / 256, 256, 0, stream>>>(m_rec, n_rec, rec_noise, W0, R);
        rnn8L<<<256, 1024, LDSB, stream>>>(input, noise, w_i, s_i, W0, w_o, s_o, h0,
                                           out, rbuf);
    } else {
        prep_wt<<<(Hc * Hc + 255) / 256, 256, 0, stream>>>(m_rec, n_rec, rec_noise, W0, R);
        rnn_scan_fb<<<Bc, 512, 0, stream>>>(input, noise, w_i, s_i, W0, w_o, s_o, h0, out);
    }
}

// Round 8
// 6805.922 us; speedup vs baseline: 1.2070x; 1.2070x over previous
//
#include <hip/hip_runtime.h>

// Problem constants (fixed by the reference)
constexpr int Bc = 64;      // batch
constexpr int Tc = 2048;    // time steps
constexpr int Ic = 3;       // input dim
constexpr int Hc = 512;     // hidden
constexpr float AL = 0.2f;  // ALPHA
constexpr float NS = 0.05f; // NOISE_STD

// Decomposition: 16 h-slices (HS=32) x 16 batch-groups (G=4) = 256 blocks.
// bid = s*16 + gb  ->  XCD = bid%8 = gb%8: a group's 16 slice-blocks share one XCD.
constexpr int G   = 4;     // batches per group
constexpr int HS  = 32;    // h per slice
constexpr int PLS = 132;   // pl row stride (16 wave-partials x 128 y-values)

// d_ws layout:
//   [0, 1MB)          WH fp32 [512 h][512 k]  (w_rec[h][k], h-major)
//   [1MB, 1MB+512KB)  rbuf u64 [16 gb][2 parity][4 b][512 h] = {tag<<32|f32}
// ---------------------------------------------------------------------------
__global__ void prep_wh(const float* __restrict__ m, const float* __restrict__ n,
                        const float* __restrict__ rn, float* __restrict__ WH, int R) {
    int id = blockIdx.x * 256 + threadIdx.x;
    if (id >= Hc * Hc) return;
    int h = id >> 9;
    int k = id & (Hc - 1);
    float acc = rn[h * Hc + k];
    for (int r = 0; r < R; ++r)
        acc = fmaf(m[h * R + r], n[k * R + r] * (1.0f / Hc), acc);
    WH[id] = acc;                               // WH[h][k]
}

__global__ void prep_wt(const float* __restrict__ m, const float* __restrict__ n,
                        const float* __restrict__ rn, float* __restrict__ WT, int R) {
    int id = blockIdx.x * 256 + threadIdx.x;
    if (id >= Hc * Hc) return;
    int k = id >> 9;
    int h = id & (Hc - 1);
    float acc = rn[h * Hc + k];
    for (int r = 0; r < R; ++r)
        acc = fmaf(m[h * R + r], n[k * R + r] * (1.0f / Hc), acc);
    WT[id] = acc;                               // WT[k][h] (fallback)
}

// L2-coherent poll load: bypass L1 (sc0), hit the XCD-shared L2.
__device__ __forceinline__ unsigned long long ld_sc0(const unsigned long long* p) {
    unsigned long long v;
    asm volatile("global_load_dwordx2 %0, %1, off sc0\n\t"
                 "s_waitcnt vmcnt(0)"
                 : "=v"(v) : "v"(p) : "memory");
    return v;
}

// NOTE: parameter names MUST NOT collide with vector member names (.x/.y/.z/.w)
#define DOT4(acc, W4, R4) \
    acc = fmaf((W4).x, (R4).x, fmaf((W4).y, (R4).y, \
          fmaf((W4).z, (R4).z, fmaf((W4).w, (R4).w, acc))))

// ---------------------------------------------------------------------------
// Main kernel: 256 blocks x 1024 threads.
// Thread (kc = tid>>4 in 0..63, hg = tid&15): tile = rows {2hg,2hg+1} x
// k [8kc,8kc+8) x 4 batches. W tile = 16 floats in 4 named float4 REGISTERS
// (loop-invariant -> register-resident; this is the whole point).
// Per step: 8 broadcast r-reads (LDS) + 64 FMA + 2 shfl-levels over kc&3 +
// 16-wave pl reduce -> owners update/publish -> pollers fetch foreign r.
// ---------------------------------------------------------------------------
__global__ __launch_bounds__(1024)
void rnn16(const float* __restrict__ input, const float* __restrict__ noise,
           const float* __restrict__ w_i, const float* __restrict__ s_i,
           const float* __restrict__ WH, const float* __restrict__ w_o,
           const float* __restrict__ s_o, const float* __restrict__ h0,
           float* __restrict__ out, unsigned long long* __restrict__ rbuf) {
    __shared__ float rp[2 * G * Hc];     // [parity][b][512]
    __shared__ float pl[16 * PLS];       // [wave][y=row*4+b] partials
    __shared__ float wo_lds[Hc];
    __shared__ float red[16];

    const int tid   = threadIdx.x;
    const int s     = blockIdx.x >> 4;   // h-slice 0..15
    const int gb    = blockIdx.x & 15;   // batch group 0..15
    const int kc    = tid >> 4;          // k-chunk 0..63 (8 k each)
    const int hg    = tid & 15;          // row-pair 0..15
    const int hbase = s * HS;
    const int b0    = gb * G;

    // --- W tile: 2 rows x 8 k = 16 floats in named registers (loop-invariant)
    const float* Wp0 = WH + (size_t)(hbase + 2 * hg + 0) * Hc + kc * 8;
    const float* Wp1 = WH + (size_t)(hbase + 2 * hg + 1) * Hc + kc * 8;
    const float4 w00 = *(const float4*)(Wp0 + 0);
    const float4 w01 = *(const float4*)(Wp0 + 4);
    const float4 w10 = *(const float4*)(Wp1 + 0);
    const float4 w11 = *(const float4*)(Wp1 + 4);

    // --- one-time LDS init: wo, r_0 (same for all 4 batches) ---
    if (tid < Hc) {
        wo_lds[tid] = w_o[tid] * s_o[0] * (1.0f / Hc);
        const float rv0 = tanhf(h0[tid]);
        #pragma unroll
        for (int b = 0; b < G; ++b) rp[b * Hc + tid] = rv0;  // parity 0
    }

    // --- owners: tid<128, b = tid>>5, hl = tid&31 (coalesced noise rows) ---
    const bool own = (tid < 128);
    const int  ob  = tid >> 5;
    const int  ohl = tid & 31;
    const int  ohm = hbase + ohl;
    float hstate = 0.f, wi0 = 0.f, wi1 = 0.f, wi2 = 0.f;
    const float* noise_b = nullptr;
    const float* inp_b   = nullptr;
    float nz = 0.f, i0 = 0.f, i1 = 0.f, i2 = 0.f;
    if (own) {
        hstate = h0[ohm];
        wi0 = w_i[0 * Hc + ohm] * s_i[0];
        wi1 = w_i[1 * Hc + ohm] * s_i[1];
        wi2 = w_i[2 * Hc + ohm] * s_i[2];
        noise_b = noise + (size_t)(b0 + ob) * Tc * Hc;
        inp_b   = input + (size_t)(b0 + ob) * Tc * Ic;
        nz = noise_b[ohm];
        i0 = inp_b[0]; i1 = inp_b[1]; i2 = inp_b[2];
    }

    // --- poller mapping: 1920 foreign (b,h) words; owners poll 1, rest 2 ---
    int wd1, wd2 = -1;
    {
        const int f1 = own ? tid : 128 + (tid - 128) * 2;
        const int fb1 = f1 / 480, fr1 = f1 % 480;
        wd1 = fb1 * Hc + fr1 + ((fr1 >= hbase) ? HS : 0);
        if (!own) {
            const int f2 = f1 + 1;
            const int fb2 = f2 / 480, fr2 = f2 % 480;
            wd2 = fb2 * Hc + fr2 + ((fr2 >= hbase) ? HS : 0);
        }
    }
    unsigned long long* rb_g = rbuf + (size_t)gb * (2 * G * Hc);

    __syncthreads();

    for (int t = 0; t < Tc; ++t) {
        const int par  = t & 1;
        const int par1 = (t + 1) & 1;

        // owner: prefetch next step's drive
        const int tn = (t + 1 < Tc) ? t + 1 : t;
        float nz_n = 0.f, i0n = 0.f, i1n = 0.f, i2n = 0.f;
        if (own) {
            nz_n = noise_b[(size_t)tn * Hc + ohm];
            i0n = inp_b[tn * Ic + 0];
            i1n = inp_b[tn * Ic + 1];
            i2n = inp_b[tn * Ic + 2];
        }

        // --- matvec: W in regs, r broadcast from LDS (8 x b128, no conflicts)
        const float* rbp = rp + par * (G * Hc) + kc * 8;
        float a00 = 0.f, a01 = 0.f, a02 = 0.f, a03 = 0.f;
        float a10 = 0.f, a11 = 0.f, a12 = 0.f, a13 = 0.f;
        {
            const float4 r0 = *(const float4*)(rbp + 0 * Hc);
            const float4 r1 = *(const float4*)(rbp + 1 * Hc);
            const float4 r2 = *(const float4*)(rbp + 2 * Hc);
            const float4 r3 = *(const float4*)(rbp + 3 * Hc);
            DOT4(a00, w00, r0); DOT4(a01, w00, r1); DOT4(a02, w00, r2); DOT4(a03, w00, r3);
            DOT4(a10, w10, r0); DOT4(a11, w10, r1); DOT4(a12, w10, r2); DOT4(a13, w10, r3);
        }
        {
            const float4 r0 = *(const float4*)(rbp + 0 * Hc + 4);
            const float4 r1 = *(const float4*)(rbp + 1 * Hc + 4);
            const float4 r2 = *(const float4*)(rbp + 2 * Hc + 4);
            const float4 r3 = *(const float4*)(rbp + 3 * Hc + 4);
            DOT4(a00, w01, r0); DOT4(a01, w01, r1); DOT4(a02, w01, r2); DOT4(a03, w01, r3);
            DOT4(a10, w11, r0); DOT4(a11, w11, r1); DOT4(a12, w11, r2); DOT4(a13, w11, r3);
        }
        // reduce over kc&3 (lane bits 4,5)
        #define RED2(a) { a += __shfl_xor(a, 16, 64); a += __shfl_xor(a, 32, 64); }
        RED2(a00) RED2(a01) RED2(a02) RED2(a03)
        RED2(a10) RED2(a11) RED2(a12) RED2(a13)
        #undef RED2

        // one writer per (wave, hg): lanes with kc&3 == 0 (lane < 16)
        if ((tid & 63) < 16) {
            float* plw = pl + (tid >> 6) * PLS + hg * 8;
            *(float4*)(plw + 0) = make_float4(a00, a01, a02, a03);  // row 2hg
            *(float4*)(plw + 4) = make_float4(a10, a11, a12, a13);  // row 2hg+1
        }
        __syncthreads();                                   // B1: pl ready

        const unsigned want = (unsigned)(t + 1);
        unsigned long long* slot = rb_g + (size_t)par1 * (G * Hc);
        float* wp_ = rp + par1 * (G * Hc);

        if (own) {
            float y = 0.f;
            #pragma unroll
            for (int w = 0; w < 16; ++w) y += pl[w * PLS + ohl * 4 + ob];
            const float di = i0 * wi0 + i1 * wi1 + i2 * wi2;
            hstate = hstate + (NS * nz + AL * di) + AL * (y - hstate);
            const float rv = tanhf(hstate);
            __hip_atomic_store(&slot[ob * Hc + ohm],
                               ((unsigned long long)want << 32) |
                               (unsigned long long)__float_as_uint(rv),
                               __ATOMIC_RELAXED, __HIP_MEMORY_SCOPE_AGENT);
            wp_[ob * Hc + ohm] = rv;
        }

        // --- poll foreign words (3x sc0 : 1x agent), write LDS on detect ---
        if (own) {
            const unsigned long long* p1 = &slot[wd1];
            unsigned long long v;
            int it = 0;
            for (;;) {
                v = ((it & 3) != 3) ? ld_sc0(p1)
                    : __hip_atomic_load(p1, __ATOMIC_RELAXED, __HIP_MEMORY_SCOPE_AGENT);
                if ((unsigned)(v >> 32) == want) break;
                ++it;
            }
            wp_[wd1] = __uint_as_float((unsigned)v);
        } else {
            const unsigned long long* p1 = &slot[wd1];
            const unsigned long long* p2 = &slot[wd2];
            bool d1 = false, d2 = false;
            int it = 0;
            for (;;) {
                if (!d1) {
                    unsigned long long v = ((it & 3) != 3) ? ld_sc0(p1)
                        : __hip_atomic_load(p1, __ATOMIC_RELAXED, __HIP_MEMORY_SCOPE_AGENT);
                    if ((unsigned)(v >> 32) == want) { wp_[wd1] = __uint_as_float((unsigned)v); d1 = true; }
                }
                if (!d2) {
                    unsigned long long v = ((it & 3) != 3) ? ld_sc0(p2)
                        : __hip_atomic_load(p2, __ATOMIC_RELAXED, __HIP_MEMORY_SCOPE_AGENT);
                    if ((unsigned)(v >> 32) == want) { wp_[wd2] = __uint_as_float((unsigned)v); d2 = true; }
                }
                if (d1 && d2) break;
                ++it;
            }
        }
        __syncthreads();                                   // B2: r_{t+1} ready

        // --- output for step t (uses r_{t+1}), rotated over the 16 slices ---
        if (((t ^ s) & 15) == 0) {
            const float* rr = rp + par1 * (G * Hc);
            // pass 0: batches b0+0, b0+1
            {
                const int bsel = tid >> 9, hh = tid & 511;
                float v = rr[bsel * Hc + hh] * wo_lds[hh];
                #pragma unroll
                for (int off = 32; off; off >>= 1) v += __shfl_xor(v, off, 64);
                if ((tid & 63) == 0) red[tid >> 6] = v;
                __syncthreads();
                if (tid == 0) {
                    float sm = 0.f;
                    #pragma unroll
                    for (int q = 0; q < 8; ++q) sm += red[q];
                    out[(size_t)(b0 + 0) * Tc + t] = sm;
                } else if (tid == 1) {
                    float sm = 0.f;
                    #pragma unroll
                    for (int q = 8; q < 16; ++q) sm += red[q];
                    out[(size_t)(b0 + 1) * Tc + t] = sm;
                }
                __syncthreads();
            }
            // pass 1: batches b0+2, b0+3
            {
                const int bsel = 2 + (tid >> 9), hh = tid & 511;
                float v = rr[bsel * Hc + hh] * wo_lds[hh];
                #pragma unroll
                for (int off = 32; off; off >>= 1) v += __shfl_xor(v, off, 64);
                if ((tid & 63) == 0) red[tid >> 6] = v;
                __syncthreads();
                if (tid == 0) {
                    float sm = 0.f;
                    #pragma unroll
                    for (int q = 0; q < 8; ++q) sm += red[q];
                    out[(size_t)(b0 + 2) * Tc + t] = sm;
                } else if (tid == 1) {
                    float sm = 0.f;
                    #pragma unroll
                    for (int q = 8; q < 16; ++q) sm += red[q];
                    out[(size_t)(b0 + 3) * Tc + t] = sm;
                }
            }
        }

        nz = nz_n; i0 = i0n; i1 = i1n; i2 = i2n;
    }
}

// ---------------------------------------------------------------------------
// Fallback (round-1 kernel) if d_ws is too small — safety net.
// ---------------------------------------------------------------------------
__launch_bounds__(512)
__global__ void rnn_scan_fb(const float* __restrict__ input, const float* __restrict__ noise,
                            const float* __restrict__ w_i, const float* __restrict__ s_i,
                            const float* __restrict__ WT, const float* __restrict__ w_o,
                            const float* __restrict__ s_o, const float* __restrict__ h0,
                            float* __restrict__ out) {
    __shared__ float r_lds[Hc];
    __shared__ float pl[4][Hc];
    __shared__ float wi_lds[Ic][Hc];
    __shared__ float red[8];

    const int tid = threadIdx.x;
    const int b   = blockIdx.x;
    const int g   = tid >> 7;
    const int j   = tid & 127;

    for (int i = 0; i < Ic; ++i) wi_lds[i][tid] = w_i[i * Hc + tid] * s_i[i];

    float h = h0[tid];
    float r_cur = tanhf(h);
    const float wo_h = w_o[tid] * s_o[0] * (1.0f / Hc);
    const float* noise_b = noise + (size_t)b * Tc * Hc;
    const float* inp_b   = input + (size_t)b * Tc * Ic;
    float nz = noise_b[tid];
    float i0 = inp_b[0], i1 = inp_b[1], i2 = inp_b[2];
    const float* Wg = WT + (g * 128) * Hc + 4 * j;
    const float* rg = r_lds + g * 128;
    __syncthreads();

    for (int t = 0; t < Tc; ++t) {
        const int tn = (t + 1 < Tc) ? t + 1 : t;
        const float nz_n = noise_b[(size_t)tn * Hc + tid];
        const float i0n = inp_b[tn * Ic + 0];
        const float i1n = inp_b[tn * Ic + 1];
        const float i2n = inp_b[tn * Ic + 2];

        r_lds[tid] = r_cur;
        __syncthreads();
        float a0 = 0.f, a1 = 0.f, a2 = 0.f, a3 = 0.f;
        #pragma unroll 4
        for (int kk = 0; kk < 128; kk += 4) {
            const float4 rv = *(const float4*)(rg + kk);
            const float4 w0 = *(const float4*)(Wg + (kk + 0) * Hc);
            const float4 w1 = *(const float4*)(Wg + (kk + 1) * Hc);
            const float4 w2 = *(const float4*)(Wg + (kk + 2) * Hc);
            const float4 w3 = *(const float4*)(Wg + (kk + 3) * Hc);
            a0 = fmaf(rv.x, w0.x, a0); a0 = fmaf(rv.y, w1.x, a0);
            a0 = fmaf(rv.z, w2.x, a0); a0 = fmaf(rv.w, w3.x, a0);
            a1 = fmaf(rv.x, w0.y, a1); a1 = fmaf(rv.y, w1.y, a1);
            a1 = fmaf(rv.z, w2.y, a1); a1 = fmaf(rv.w, w3.y, a1);
            a2 = fmaf(rv.x, w0.z, a2); a2 = fmaf(rv.y, w1.z, a2);
            a2 = fmaf(rv.z, w2.z, a2); a2 = fmaf(rv.w, w3.z, a2);
            a3 = fmaf(rv.x, w0.w, a3); a3 = fmaf(rv.y, w1.w, a3);
            a3 = fmaf(rv.z, w2.w, a3); a3 = fmaf(rv.w, w3.w, a3);
        }
        *(float4*)&pl[g][4 * j] = make_float4(a0, a1, a2, a3);
        __syncthreads();

        const float y  = pl[0][tid] + pl[1][tid] + pl[2][tid] + pl[3][tid];
        const float di = i0 * wi_lds[0][tid] + i1 * wi_lds[1][tid] + i2 * wi_lds[2][tid];
        h = h + (NS * nz + AL * di) + AL * (y - h);
        r_cur = tanhf(h);

        float p = r_cur * wo_h;
        #pragma unroll
        for (int off = 32; off; off >>= 1) p += __shfl_xor(p, off, 64);
        if ((tid & 63) == 0) red[tid >> 6] = p;
        __syncthreads();
        if (tid == 0)
            out[(size_t)b * Tc + t] = red[0] + red[1] + red[2] + red[3] +
                                      red[4] + red[5] + red[6] + red[7];
        nz = nz_n; i0 = i0n; i1 = i1n; i2 = i2n;
    }
}

extern "C" void kernel_launch(void* const* d_in, const int* in_sizes, int n_in,
                              void* d_out, int out_size, void* d_ws, size_t ws_size,
                              hipStream_t stream) {
    (void)n_in; (void)out_size;
    const float* input     = (const float*)d_in[0];
    const float* noise     = (const float*)d_in[1];
    const float* w_i       = (const float*)d_in[2];
    const float* s_i       = (const float*)d_in[3];
    const float* m_rec     = (const float*)d_in[4];
    const float* n_rec     = (const float*)d_in[5];
    const float* rec_noise = (const float*)d_in[6];
    const float* w_o       = (const float*)d_in[7];
    const float* s_o       = (const float*)d_in[8];
    const float* h0        = (const float*)d_in[9];
    float* out = (float*)d_out;

    const int R = in_sizes[4] / Hc;

    float* W0 = (float*)d_ws;   // WH (main) or WT (fallback)
    const size_t w_bytes  = (size_t)Hc * Hc * sizeof(float);
    const size_t rb_bytes = (size_t)16 * 2 * G * Hc * sizeof(unsigned long long);

    if (ws_size >= w_bytes + rb_bytes) {
        unsigned long long* rbuf = (unsigned long long*)((char*)d_ws + w_bytes);
        hipMemsetAsync(rbuf, 0, rb_bytes, stream);  // reset tags (replay-safe)
        prep_wh<<<(Hc * Hc + 255) / 256, 256, 0, stream>>>(m_rec, n_rec, rec_noise, W0, R);
        rnn16<<<256, 1024, 0, stream>>>(input, noise, w_i, s_i, W0, w_o, s_o, h0,
                                        out, rbuf);
    } else {
        prep_wt<<<(Hc * Hc + 255) / 256, 256, 0, stream>>>(m_rec, n_rec, rec_noise, W0, R);
        rnn_scan_fb<<<Bc, 512, 0, stream>>>(input, noise, w_i, s_i, W0, w_o, s_o, h0, out);
    }
}

// Round 9
// 6069.095 us; speedup vs baseline: 1.3535x; 1.1214x over previous
//
#include <hip/hip_runtime.h>

// Problem constants (fixed by the reference)
constexpr int Bc = 64;      // batch
constexpr int Tc = 2048;    // time steps
constexpr int Ic = 3;       // input dim
constexpr int Hc = 512;     // hidden
constexpr float AL = 0.2f;  // ALPHA
constexpr float NS = 0.05f; // NOISE_STD

// Decomposition (round-8 proven): 16 h-slices (HS=32) x 16 batch-groups (G=4).
// bid = s*16 + gb -> XCD = bid%8 = gb%8: a group's 16 slice-blocks share an XCD.
constexpr int G   = 4;
constexpr int HS  = 32;
constexpr int PLS = 132;

// d_ws layout:
//   [0, 1MB)            WH fp32 [512 h][512 k]
//   [1MB, 1.5MB)        fast rbuf u64 [16 gb][2 par][4 b][512 h] (plain stores, L2)
//   [1.5MB, 2MB)        slow rbuf u64 (agent-scope atomics, MALL)
//   [2MB, 10MB)         part fp32 [16 s][64 b][2048 t]
//   [10MB, +4)          epoch u32 (monotonic across calls; never reset)
constexpr size_t WS_WH    = 0;
constexpr size_t WS_FAST  = 1u << 20;
constexpr size_t WS_SLOW  = WS_FAST + (512u << 10);
constexpr size_t WS_PART  = 2u << 20;
constexpr size_t WS_EPOCH = 10u << 20;
constexpr size_t WS_NEED  = WS_EPOCH + 64;

// ---------------------------------------------------------------------------
__global__ void prep_wh(const float* __restrict__ m, const float* __restrict__ n,
                        const float* __restrict__ rn, float* __restrict__ WH, int R) {
    int id = blockIdx.x * 256 + threadIdx.x;
    if (id >= Hc * Hc) return;
    int h = id >> 9;
    int k = id & (Hc - 1);
    float acc = rn[h * Hc + k];
    for (int r = 0; r < R; ++r)
        acc = fmaf(m[h * R + r], n[k * R + r] * (1.0f / Hc), acc);
    WH[id] = acc;                               // WH[h][k]
}

__global__ void prep_wt(const float* __restrict__ m, const float* __restrict__ n,
                        const float* __restrict__ rn, float* __restrict__ WT, int R) {
    int id = blockIdx.x * 256 + threadIdx.x;
    if (id >= Hc * Hc) return;
    int k = id >> 9;
    int h = id & (Hc - 1);
    float acc = rn[h * Hc + k];
    for (int r = 0; r < R; ++r)
        acc = fmaf(m[h * R + r], n[k * R + r] * (1.0f / Hc), acc);
    WT[id] = acc;                               // WT[k][h] (fallback)
}

__global__ void bump_epoch(unsigned* e) {
    if (threadIdx.x == 0 && blockIdx.x == 0) *e += 4096u;
}

// Fast-path poll: L1-bypassing (sc0) load -> hits the XCD-shared L2.
__device__ __forceinline__ unsigned long long ld_sc0(const unsigned long long* p) {
    unsigned long long v;
    asm volatile("global_load_dwordx2 %0, %1, off sc0\n\t"
                 "s_waitcnt vmcnt(0)"
                 : "=v"(v) : "v"(p) : "memory");
    return v;
}
// Pipelined pair: both loads in flight, ONE waitcnt (halves poll latency).
__device__ __forceinline__ void ld_sc0x2(const unsigned long long* p1,
                                         const unsigned long long* p2,
                                         unsigned long long& v1,
                                         unsigned long long& v2) {
    asm volatile("global_load_dwordx2 %0, %2, off sc0\n\t"
                 "global_load_dwordx2 %1, %3, off sc0\n\t"
                 "s_waitcnt vmcnt(0)"
                 : "=&v"(v1), "=&v"(v2) : "v"(p1), "v"(p2) : "memory");
}
// Fast-path publish: plain store (CDNA L1 is write-through -> lands in L2).
__device__ __forceinline__ void st_plain(unsigned long long* p, unsigned long long v) {
    asm volatile("global_store_dwordx2 %0, %1, off"
                 :: "v"(p), "v"(v) : "memory");
}

// NOTE: macro parameter names must not collide with vector members (.x/.y/.z/.w)
#define DOT4(acc, W4, R4) \
    acc = fmaf((W4).x, (R4).x, fmaf((W4).y, (R4).y, \
          fmaf((W4).z, (R4).z, fmaf((W4).w, (R4).w, acc))))

// ---------------------------------------------------------------------------
// Main kernel: 256 blocks x 1024 threads (geometry identical to round 8).
// Changes: dual-publish fast(L2)/slow(MALL), epoch tags, output partials
// streamed to `part` (no in-loop cross-wave output reduction).
// ---------------------------------------------------------------------------
__global__ __launch_bounds__(1024)
__attribute__((amdgpu_waves_per_eu(4, 4)))
void rnn16x(const float* __restrict__ input, const float* __restrict__ noise,
            const float* __restrict__ w_i, const float* __restrict__ s_i,
            const float* __restrict__ WH, const float* __restrict__ w_o,
            const float* __restrict__ s_o, const float* __restrict__ h0,
            float* __restrict__ part,
            unsigned long long* __restrict__ fbuf,
            unsigned long long* __restrict__ sbuf,
            const unsigned* __restrict__ epoch) {
    __shared__ float rp[2 * G * Hc];     // [parity][b][512]
    __shared__ float pl[16 * PLS];       // [wave][y] matvec partials

    const int tid   = threadIdx.x;
    const int s     = blockIdx.x >> 4;   // h-slice 0..15
    const int gb    = blockIdx.x & 15;   // batch group 0..15
    const int kc    = tid >> 4;          // k-chunk 0..63 (8 k each)
    const int hg    = tid & 15;          // row-pair 0..15
    const int hbase = s * HS;
    const int b0    = gb * G;
    const unsigned ep = *epoch;

    // --- W tile: 2 rows x 8 k = 16 floats in registers (round-8 proven) ---
    const float* Wp0 = WH + (size_t)(hbase + 2 * hg + 0) * Hc + kc * 8;
    const float* Wp1 = WH + (size_t)(hbase + 2 * hg + 1) * Hc + kc * 8;
    const float4 w00 = *(const float4*)(Wp0 + 0);
    const float4 w01 = *(const float4*)(Wp0 + 4);
    const float4 w10 = *(const float4*)(Wp1 + 0);
    const float4 w11 = *(const float4*)(Wp1 + 4);

    // --- r_0 into parity-0 (same for all 4 batches) ---
    if (tid < Hc) {
        const float rv0 = tanhf(h0[tid]);
        #pragma unroll
        for (int b = 0; b < G; ++b) rp[b * Hc + tid] = rv0;
    }

    // --- owners: tid<128, ob = tid>>5 (batch), ohl = tid&31 (row) ---
    const bool own = (tid < 128);
    const int  ob  = tid >> 5;
    const int  ohl = tid & 31;
    const int  ohm = hbase + ohl;
    float hstate = 0.f, wi0 = 0.f, wi1 = 0.f, wi2 = 0.f, wo_own = 0.f;
    const float* noise_b = nullptr;
    const float* inp_b   = nullptr;
    float nz = 0.f, i0 = 0.f, i1 = 0.f, i2 = 0.f;
    if (own) {
        hstate = h0[ohm];
        wi0 = w_i[0 * Hc + ohm] * s_i[0];
        wi1 = w_i[1 * Hc + ohm] * s_i[1];
        wi2 = w_i[2 * Hc + ohm] * s_i[2];
        wo_own = w_o[ohm] * s_o[0] * (1.0f / Hc);
        noise_b = noise + (size_t)(b0 + ob) * Tc * Hc;
        inp_b   = input + (size_t)(b0 + ob) * Tc * Ic;
        nz = noise_b[ohm];
        i0 = inp_b[0]; i1 = inp_b[1]; i2 = inp_b[2];
    }

    // --- poller mapping (round-8): 1920 foreign words; owners 1, others 2 ---
    int wd1, wd2 = -1;
    {
        const int f1 = own ? tid : 128 + (tid - 128) * 2;
        const int fb1 = f1 / 480, fr1 = f1 % 480;
        wd1 = fb1 * Hc + fr1 + ((fr1 >= hbase) ? HS : 0);
        if (!own) {
            const int f2 = f1 + 1;
            const int fb2 = f2 / 480, fr2 = f2 % 480;
            wd2 = fb2 * Hc + fr2 + ((fr2 >= hbase) ? HS : 0);
        }
    }
    unsigned long long* fb_g = fbuf + (size_t)gb * (2 * G * Hc);
    unsigned long long* sb_g = sbuf + (size_t)gb * (2 * G * Hc);
    float* part_b = part + ((size_t)s * Bc + b0) * Tc;   // + ob*Tc + t

    __syncthreads();

    for (int t = 0; t < Tc; ++t) {
        const int par  = t & 1;
        const int par1 = (t + 1) & 1;

        // owners: prefetch next step's drive
        const int tn = (t + 1 < Tc) ? t + 1 : t;
        float nz_n = 0.f, i0n = 0.f, i1n = 0.f, i2n = 0.f;
        if (own) {
            nz_n = noise_b[(size_t)tn * Hc + ohm];
            i0n = inp_b[tn * Ic + 0];
            i1n = inp_b[tn * Ic + 1];
            i2n = inp_b[tn * Ic + 2];
        }

        // --- matvec: W in regs, r broadcast from LDS (round-8 verbatim) ---
        const float* rbp = rp + par * (G * Hc) + kc * 8;
        float a00 = 0.f, a01 = 0.f, a02 = 0.f, a03 = 0.f;
        float a10 = 0.f, a11 = 0.f, a12 = 0.f, a13 = 0.f;
        {
            const float4 r0 = *(const float4*)(rbp + 0 * Hc);
            const float4 r1 = *(const float4*)(rbp + 1 * Hc);
            const float4 r2 = *(const float4*)(rbp + 2 * Hc);
            const float4 r3 = *(const float4*)(rbp + 3 * Hc);
            DOT4(a00, w00, r0); DOT4(a01, w00, r1); DOT4(a02, w00, r2); DOT4(a03, w00, r3);
            DOT4(a10, w10, r0); DOT4(a11, w10, r1); DOT4(a12, w10, r2); DOT4(a13, w10, r3);
        }
        {
            const float4 r0 = *(const float4*)(rbp + 0 * Hc + 4);
            const float4 r1 = *(const float4*)(rbp + 1 * Hc + 4);
            const float4 r2 = *(const float4*)(rbp + 2 * Hc + 4);
            const float4 r3 = *(const float4*)(rbp + 3 * Hc + 4);
            DOT4(a00, w01, r0); DOT4(a01, w01, r1); DOT4(a02, w01, r2); DOT4(a03, w01, r3);
            DOT4(a10, w11, r0); DOT4(a11, w11, r1); DOT4(a12, w11, r2); DOT4(a13, w11, r3);
        }
        #define RED2(a) { a += __shfl_xor(a, 16, 64); a += __shfl_xor(a, 32, 64); }
        RED2(a00) RED2(a01) RED2(a02) RED2(a03)
        RED2(a10) RED2(a11) RED2(a12) RED2(a13)
        #undef RED2

        if ((tid & 63) < 16) {
            float* plw = pl + (tid >> 6) * PLS + hg * 8;
            *(float4*)(plw + 0) = make_float4(a00, a01, a02, a03);  // row 2hg
            *(float4*)(plw + 4) = make_float4(a10, a11, a12, a13);  // row 2hg+1
        }
        __syncthreads();                                   // B1: pl ready

        const unsigned want = ep + (unsigned)(t + 1);
        unsigned long long* fslot = fb_g + (size_t)par1 * (G * Hc);
        unsigned long long* sslot = sb_g + (size_t)par1 * (G * Hc);
        float* wp_ = rp + par1 * (G * Hc);

        if (own) {
            float y = 0.f;
            #pragma unroll
            for (int w = 0; w < 16; ++w) y += pl[w * PLS + ohl * 4 + ob];
            const float di = i0 * wi0 + i1 * wi1 + i2 * wi2;
            hstate = hstate + (NS * nz + AL * di) + AL * (y - hstate);
            const float rv = tanhf(hstate);
            const unsigned long long word =
                ((unsigned long long)want << 32) | (unsigned long long)__float_as_uint(rv);
            st_plain(&fslot[ob * Hc + ohm], word);          // fast: L2 (same XCD)
            __hip_atomic_store(&sslot[ob * Hc + ohm], word,
                               __ATOMIC_RELAXED, __HIP_MEMORY_SCOPE_AGENT); // slow: MALL
            wp_[ob * Hc + ohm] = rv;

            // output partial for this slice (off the exchange critical path):
            float pr = rv * wo_own;
            #pragma unroll
            for (int m = 16; m; m >>= 1) pr += __shfl_xor(pr, m, 32);
            if ((tid & 31) == 0) part_b[(size_t)ob * Tc + t] = pr;
        }

        // --- poll foreign words: fast L2 polls, slow MALL fallback every 4th ---
        if (own) {
            const unsigned long long* fp1 = &fslot[wd1];
            const unsigned long long* sp1 = &sslot[wd1];
            unsigned long long v;
            int it = 0;
            for (;;) {
                v = ((it & 3) != 3) ? ld_sc0(fp1)
                    : __hip_atomic_load(sp1, __ATOMIC_RELAXED, __HIP_MEMORY_SCOPE_AGENT);
                if ((unsigned)(v >> 32) == want) break;
                ++it;
            }
            wp_[wd1] = __uint_as_float((unsigned)v);
        } else {
            const unsigned long long* fp1 = &fslot[wd1];
            const unsigned long long* fp2 = &fslot[wd2];
            const unsigned long long* sp1 = &sslot[wd1];
            const unsigned long long* sp2 = &sslot[wd2];
            bool d1 = false, d2 = false;
            int it = 0;
            for (;;) {
                unsigned long long v1, v2;
                if ((it & 3) != 3) {
                    ld_sc0x2(fp1, fp2, v1, v2);
                } else {
                    v1 = __hip_atomic_load(sp1, __ATOMIC_RELAXED, __HIP_MEMORY_SCOPE_AGENT);
                    v2 = __hip_atomic_load(sp2, __ATOMIC_RELAXED, __HIP_MEMORY_SCOPE_AGENT);
                }
                if (!d1 && (unsigned)(v1 >> 32) == want) { wp_[wd1] = __uint_as_float((unsigned)v1); d1 = true; }
                if (!d2 && (unsigned)(v2 >> 32) == want) { wp_[wd2] = __uint_as_float((unsigned)v2); d2 = true; }
                if (d1 && d2) break;
                ++it;
            }
        }
        __syncthreads();                                   // B2: r_{t+1} ready

        nz = nz_n; i0 = i0n; i1 = i1n; i2 = i2n;
    }
}

// ---------------------------------------------------------------------------
// Epilogue: out[b][t] = sum over 16 slices of part[s][b][t]
// ---------------------------------------------------------------------------
__global__ void out_reduce16(const float* __restrict__ part, float* __restrict__ out) {
    const int id = blockIdx.x * 256 + threadIdx.x;
    if (id >= Bc * Tc) return;
    const int b = id >> 11, t = id & (Tc - 1);
    float sm = 0.f;
    #pragma unroll
    for (int sl = 0; sl < 16; ++sl)
        sm += part[((size_t)sl * Bc + b) * Tc + t];
    out[id] = sm;
}

// ---------------------------------------------------------------------------
// Fallback (round-1 kernel) if d_ws is too small — safety net.
// ---------------------------------------------------------------------------
__launch_bounds__(512)
__global__ void rnn_scan_fb(const float* __restrict__ input, const float* __restrict__ noise,
                            const float* __restrict__ w_i, const float* __restrict__ s_i,
                            const float* __restrict__ WT, const float* __restrict__ w_o,
                            const float* __restrict__ s_o, const float* __restrict__ h0,
                            float* __restrict__ out) {
    __shared__ float r_lds[Hc];
    __shared__ float pl[4][Hc];
    __shared__ float wi_lds[Ic][Hc];
    __shared__ float red[8];

    const int tid = threadIdx.x;
    const int b   = blockIdx.x;
    const int g   = tid >> 7;
    const int j   = tid & 127;

    for (int i = 0; i < Ic; ++i) wi_lds[i][tid] = w_i[i * Hc + tid] * s_i[i];

    float h = h0[tid];
    float r_cur = tanhf(h);
    const float wo_h = w_o[tid] * s_o[0] * (1.0f / Hc);
    const float* noise_b = noise + (size_t)b * Tc * Hc;
    const float* inp_b   = input + (size_t)b * Tc * Ic;
    float nz = noise_b[tid];
    float i0 = inp_b[0], i1 = inp_b[1], i2 = inp_b[2];
    const float* Wg = WT + (g * 128) * Hc + 4 * j;
    const float* rg = r_lds + g * 128;
    __syncthreads();

    for (int t = 0; t < Tc; ++t) {
        const int tn = (t + 1 < Tc) ? t + 1 : t;
        const float nz_n = noise_b[(size_t)tn * Hc + tid];
        const float i0n = inp_b[tn * Ic + 0];
        const float i1n = inp_b[tn * Ic + 1];
        const float i2n = inp_b[tn * Ic + 2];

        r_lds[tid] = r_cur;
        __syncthreads();
        float a0 = 0.f, a1 = 0.f, a2 = 0.f, a3 = 0.f;
        #pragma unroll 4
        for (int kk = 0; kk < 128; kk += 4) {
            const float4 rv = *(const float4*)(rg + kk);
            const float4 w0 = *(const float4*)(Wg + (kk + 0) * Hc);
            const float4 w1 = *(const float4*)(Wg + (kk + 1) * Hc);
            const float4 w2 = *(const float4*)(Wg + (kk + 2) * Hc);
            const float4 w3 = *(const float4*)(Wg + (kk + 3) * Hc);
            a0 = fmaf(rv.x, w0.x, a0); a0 = fmaf(rv.y, w1.x, a0);
            a0 = fmaf(rv.z, w2.x, a0); a0 = fmaf(rv.w, w3.x, a0);
            a1 = fmaf(rv.x, w0.y, a1); a1 = fmaf(rv.y, w1.y, a1);
            a1 = fmaf(rv.z, w2.y, a1); a1 = fmaf(rv.w, w3.y, a1);
            a2 = fmaf(rv.x, w0.z, a2); a2 = fmaf(rv.y, w1.z, a2);
            a2 = fmaf(rv.z, w2.z, a2); a2 = fmaf(rv.w, w3.z, a2);
            a3 = fmaf(rv.x, w0.w, a3); a3 = fmaf(rv.y, w1.w, a3);
            a3 = fmaf(rv.z, w2.w, a3); a3 = fmaf(rv.w, w3.w, a3);
        }
        *(float4*)&pl[g][4 * j] = make_float4(a0, a1, a2, a3);
        __syncthreads();

        const float y  = pl[0][tid] + pl[1][tid] + pl[2][tid] + pl[3][tid];
        const float di = i0 * wi_lds[0][tid] + i1 * wi_lds[1][tid] + i2 * wi_lds[2][tid];
        h = h + (NS * nz + AL * di) + AL * (y - h);
        r_cur = tanhf(h);

        float p = r_cur * wo_h;
        #pragma unroll
        for (int off = 32; off; off >>= 1) p += __shfl_xor(p, off, 64);
        if ((tid & 63) == 0) red[tid >> 6] = p;
        __syncthreads();
        if (tid == 0)
            out[(size_t)b * Tc + t] = red[0] + red[1] + red[2] + red[3] +
                                      red[4] + red[5] + red[6] + red[7];
        nz = nz_n; i0 = i0n; i1 = i1n; i2 = i2n;
    }
}

extern "C" void kernel_launch(void* const* d_in, const int* in_sizes, int n_in,
                              void* d_out, int out_size, void* d_ws, size_t ws_size,
                              hipStream_t stream) {
    (void)n_in; (void)out_size;
    const float* input     = (const float*)d_in[0];
    const float* noise     = (const float*)d_in[1];
    const float* w_i       = (const float*)d_in[2];
    const float* s_i       = (const float*)d_in[3];
    const float* m_rec     = (const float*)d_in[4];
    const float* n_rec     = (const float*)d_in[5];
    const float* rec_noise = (const float*)d_in[6];
    const float* w_o       = (const float*)d_in[7];
    const float* s_o       = (const float*)d_in[8];
    const float* h0        = (const float*)d_in[9];
    float* out = (float*)d_out;

    const int R = in_sizes[4] / Hc;
    char* ws = (char*)d_ws;

    if (ws_size >= WS_NEED) {
        float* WH = (float*)(ws + WS_WH);
        unsigned long long* fbuf = (unsigned long long*)(ws + WS_FAST);
        unsigned long long* sbuf = (unsigned long long*)(ws + WS_SLOW);
        float* part = (float*)(ws + WS_PART);
        unsigned* epoch = (unsigned*)(ws + WS_EPOCH);

        bump_epoch<<<1, 1, 0, stream>>>(epoch);   // stale tags can never match
        prep_wh<<<(Hc * Hc + 255) / 256, 256, 0, stream>>>(m_rec, n_rec, rec_noise, WH, R);
        rnn16x<<<256, 1024, 0, stream>>>(input, noise, w_i, s_i, WH, w_o, s_o, h0,
                                         part, fbuf, sbuf, epoch);
        out_reduce16<<<(Bc * Tc + 255) / 256, 256, 0, stream>>>(part, out);
    } else {
        float* WT = (float*)(ws + WS_WH);
        prep_wt<<<(Hc * Hc + 255) / 256, 256, 0, stream>>>(m_rec, n_rec, rec_noise, WT, R);
        rnn_scan_fb<<<Bc, 512, 0, stream>>>(input, noise, w_i, s_i, WT, w_o, s_o, h0, out);
    }
}